// Round 1
// baseline (2569.914 us; speedup 1.0000x reference)
//
#include <hip/hip_runtime.h>

// ---------------------------------------------------------------- types/helpers
typedef __bf16 bf16x8 __attribute__((ext_vector_type(8)));
typedef float  f32x4  __attribute__((ext_vector_type(4)));

#define DEV __device__ __forceinline__

DEV ushort f2bf(float f) {                       // fp32 -> bf16 RNE
  unsigned u = __builtin_bit_cast(unsigned, f);
  u += 0x7FFFu + ((u >> 16) & 1u);
  return (ushort)(u >> 16);
}
DEV float bf2f(ushort u) { return __builtin_bit_cast(float, ((unsigned)u) << 16); }
DEV unsigned pk2(ushort a, ushort b) { return (unsigned)a | ((unsigned)b << 16); }

DEV f32x4 mfma16(bf16x8 a, bf16x8 b, f32x4 c) {
  return __builtin_amdgcn_mfma_f32_16x16x32_bf16(a, b, c, 0, 0, 0);
}

DEV float gelu_f(float x) {                      // jax.nn.gelu approximate=True
  float x3 = x * x * x;
  return 0.5f * x * (1.f + tanhf(0.7978845608028654f * (x + 0.044715f * x3)));
}

#define SEQ  1024
#define NBAT 4
#define CDIM 256
#define EDIM 512
#define NLAY 6
#define NHEAD 8
#define HDIM 32
#define IDIM 1024
#define NVOC 50304
#define NROWS (NBAT * SEQ)   // 4096

// ---------------------------------------------------------------- fp32 -> bf16 convert
__global__ __launch_bounds__(256) void cvt_k(const float* __restrict__ src,
                                             ushort* __restrict__ dst, int n4) {
  int i = blockIdx.x * blockDim.x + threadIdx.x;
  int stride = gridDim.x * blockDim.x;
  for (; i < n4; i += stride) {
    float4 f = ((const float4*)src)[i];
    ushort4 u; u.x = f2bf(f.x); u.y = f2bf(f.y); u.z = f2bf(f.z); u.w = f2bf(f.w);
    ((ushort4*)dst)[i] = u;
  }
}

// ---------------------------------------------------------------- embed gather + LN (E=512)
__global__ __launch_bounds__(64) void embed_ln_k(const int* __restrict__ ids,
                                                 const float* __restrict__ ew,
                                                 const float* __restrict__ w,
                                                 const float* __restrict__ b,
                                                 ushort* __restrict__ tok) {
  int m = blockIdx.x, t = threadIdx.x;
  const float* row = ew + (size_t)ids[m] * EDIM;
  float4 v0 = *(const float4*)(row + t * 8);
  float4 v1 = *(const float4*)(row + t * 8 + 4);
  float sm = v0.x + v0.y + v0.z + v0.w + v1.x + v1.y + v1.z + v1.w;
  float sq = v0.x*v0.x + v0.y*v0.y + v0.z*v0.z + v0.w*v0.w
           + v1.x*v1.x + v1.y*v1.y + v1.z*v1.z + v1.w*v1.w;
#pragma unroll
  for (int msk = 1; msk <= 32; msk <<= 1) { sm += __shfl_xor(sm, msk); sq += __shfl_xor(sq, msk); }
  float mean = sm * (1.f / EDIM);
  float var  = sq * (1.f / EDIM) - mean * mean;
  float inv  = rsqrtf(var + 1e-5f);
  float4 w0 = *(const float4*)(w + t * 8), w1 = *(const float4*)(w + t * 8 + 4);
  float4 b0 = *(const float4*)(b + t * 8), b1 = *(const float4*)(b + t * 8 + 4);
  ushort4 u0, u1;
  u0.x = f2bf((v0.x - mean) * inv * w0.x + b0.x);
  u0.y = f2bf((v0.y - mean) * inv * w0.y + b0.y);
  u0.z = f2bf((v0.z - mean) * inv * w0.z + b0.z);
  u0.w = f2bf((v0.w - mean) * inv * w0.w + b0.w);
  u1.x = f2bf((v1.x - mean) * inv * w1.x + b1.x);
  u1.y = f2bf((v1.y - mean) * inv * w1.y + b1.y);
  u1.z = f2bf((v1.z - mean) * inv * w1.z + b1.z);
  u1.w = f2bf((v1.w - mean) * inv * w1.w + b1.w);
  *(ushort4*)(tok + (size_t)m * EDIM + t * 8)     = u0;
  *(ushort4*)(tok + (size_t)m * EDIM + t * 8 + 4) = u1;
}

// ---------------------------------------------------------------- LayerNorm (C=256) -> bf16, 1 or 2 outputs
template <bool DUAL>
__global__ __launch_bounds__(64) void ln_k(const float* __restrict__ x,
                                           const float* __restrict__ w1, const float* __restrict__ b1,
                                           const float* __restrict__ w2, const float* __restrict__ b2,
                                           ushort* __restrict__ o1, ushort* __restrict__ o2) {
  int m = blockIdx.x, t = threadIdx.x;
  const float* row = x + (size_t)m * CDIM;
  float4 v = *(const float4*)(row + t * 4);
  float sm = v.x + v.y + v.z + v.w;
  float sq = v.x*v.x + v.y*v.y + v.z*v.z + v.w*v.w;
#pragma unroll
  for (int msk = 1; msk <= 32; msk <<= 1) { sm += __shfl_xor(sm, msk); sq += __shfl_xor(sq, msk); }
  float mean = sm * (1.f / CDIM);
  float var  = sq * (1.f / CDIM) - mean * mean;
  float inv  = rsqrtf(var + 1e-5f);
  float n0 = (v.x - mean) * inv, n1 = (v.y - mean) * inv, n2 = (v.z - mean) * inv, n3 = (v.w - mean) * inv;
  {
    float4 wv = *(const float4*)(w1 + t * 4), bv = *(const float4*)(b1 + t * 4);
    ushort4 u; u.x = f2bf(n0*wv.x+bv.x); u.y = f2bf(n1*wv.y+bv.y); u.z = f2bf(n2*wv.z+bv.z); u.w = f2bf(n3*wv.w+bv.w);
    *(ushort4*)(o1 + (size_t)m * CDIM + t * 4) = u;
  }
  if constexpr (DUAL) {
    float4 wv = *(const float4*)(w2 + t * 4), bv = *(const float4*)(b2 + t * 4);
    ushort4 u; u.x = f2bf(n0*wv.x+bv.x); u.y = f2bf(n1*wv.y+bv.y); u.z = f2bf(n2*wv.z+bv.z); u.w = f2bf(n3*wv.w+bv.w);
    *(ushort4*)(o2 + (size_t)m * CDIM + t * 4) = u;
  }
}

// ---------------------------------------------------------------- generic 128x128 MFMA GEMM
// C[M,N] = A[M,K](bf16) * W[N,K]^T (+bias) (+gelu) (+accumulate) ; W fp32 or bf16
enum { GF_BIAS = 1, GF_GELU = 2, GF_ACC = 4, GF_BF16O = 8, GF_WF32 = 16 };

template <int FLAGS>
__global__ __launch_bounds__(256) void gemm_k(const ushort* __restrict__ A, int lda,
                                              const void* __restrict__ Wv, int ldw,
                                              const float* __restrict__ bias,
                                              void* __restrict__ C, int ldc, int K) {
  __shared__ __attribute__((aligned(16))) ushort lsA[128 * 32];
  __shared__ __attribute__((aligned(16))) ushort lsB[128 * 32];
  const int tid = threadIdx.x, lane = tid & 63, wave = tid >> 6;
  const int wm = wave >> 1, wn = wave & 1;
  const int row0 = blockIdx.x * 128, col0 = blockIdx.y * 128;
  const int l15 = lane & 15, koff = (lane >> 4) * 8;

  f32x4 acc[4][4] = {};
  for (int k0 = 0; k0 < K; k0 += 32) {
    __syncthreads();
#pragma unroll
    for (int p = 0; p < 2; ++p) {
      int c = tid + p * 256;          // 512 chunks of 8 bf16
      int r = c >> 2, k8 = (c & 3) * 8;
      // A tile (bf16 source)
      *(uint4*)(&lsA[c * 8]) = *(const uint4*)(A + (size_t)(row0 + r) * lda + k0 + k8);
      // W tile
      if constexpr (FLAGS & GF_WF32) {
        const float* gw = (const float*)Wv + (size_t)(col0 + r) * ldw + k0 + k8;
        float4 f0 = *(const float4*)gw, f1 = *(const float4*)(gw + 4);
        uint4 vw;
        vw.x = pk2(f2bf(f0.x), f2bf(f0.y)); vw.y = pk2(f2bf(f0.z), f2bf(f0.w));
        vw.z = pk2(f2bf(f1.x), f2bf(f1.y)); vw.w = pk2(f2bf(f1.z), f2bf(f1.w));
        *(uint4*)(&lsB[c * 8]) = vw;
      } else {
        *(uint4*)(&lsB[c * 8]) = *(const uint4*)((const ushort*)Wv + (size_t)(col0 + r) * ldw + k0 + k8);
      }
    }
    __syncthreads();
    bf16x8 af[4], bfr[4];
#pragma unroll
    for (int mt = 0; mt < 4; ++mt)
      af[mt] = __builtin_bit_cast(bf16x8, *(const uint4*)(&lsA[(wm * 64 + mt * 16 + l15) * 32 + koff]));
#pragma unroll
    for (int nt = 0; nt < 4; ++nt)
      bfr[nt] = __builtin_bit_cast(bf16x8, *(const uint4*)(&lsB[(wn * 64 + nt * 16 + l15) * 32 + koff]));
#pragma unroll
    for (int mt = 0; mt < 4; ++mt)
#pragma unroll
      for (int nt = 0; nt < 4; ++nt)
        acc[mt][nt] = mfma16(af[mt], bfr[nt], acc[mt][nt]);
  }
  // epilogue: C/D layout col = lane&15, row = (lane>>4)*4 + r
#pragma unroll
  for (int mt = 0; mt < 4; ++mt) {
#pragma unroll
    for (int nt = 0; nt < 4; ++nt) {
      int col = col0 + wn * 64 + nt * 16 + l15;
      float bv = (FLAGS & GF_BIAS) ? bias[col] : 0.f;
      int rowb = row0 + wm * 64 + mt * 16 + (lane >> 4) * 4;
#pragma unroll
      for (int r = 0; r < 4; ++r) {
        float v = acc[mt][nt][r] + bv;
        if constexpr (FLAGS & GF_GELU) v = gelu_f(v);
        size_t off = (size_t)(rowb + r) * ldc + col;
        if constexpr (FLAGS & GF_ACC)        ((float*)C)[off] += v;
        else if constexpr (FLAGS & GF_BF16O) ((ushort*)C)[off] = f2bf(v);
        else                                 ((float*)C)[off] = v;
      }
    }
  }
}

// ---------------------------------------------------------------- sequential context scan (1 block)
// ctx_{t+1} = LN(gelu(W_c ctx_t + P[t])),  P[t] precomputed = W_e emb_t + ctx_b
__global__ __launch_bounds__(256) void scan_k(const float* __restrict__ ctx_w,
                                              const float* __restrict__ prev_ctx,
                                              const float* __restrict__ P,
                                              const float* __restrict__ cn_w,
                                              const float* __restrict__ cn_b,
                                              float* __restrict__ x) {
  __shared__ __attribute__((aligned(16))) ushort ctx_lds[4 * 288];  // [b][o] stride 288
  __shared__ __attribute__((aligned(16))) float  h_lds[4 * 256];
  const int tid = threadIdx.x, lane = tid & 63, wave = tid >> 6;
  const int l15 = lane & 15, lhi = lane >> 4;

  // static weight B-fragments: wave owns outputs [wave*64, wave*64+64)
  bf16x8 wf[4][8];
#pragma unroll
  for (int nt = 0; nt < 4; ++nt)
#pragma unroll
    for (int kt = 0; kt < 8; ++kt) {
      int n = wave * 64 + nt * 16 + l15;
      int k = kt * 32 + lhi * 8;
      const float* s = ctx_w + (size_t)n * 768 + k;   // W_c = ctx_w[:, :256]
      float4 f0 = *(const float4*)s, f1 = *(const float4*)(s + 4);
      uint4 vw;
      vw.x = pk2(f2bf(f0.x), f2bf(f0.y)); vw.y = pk2(f2bf(f0.z), f2bf(f0.w));
      vw.z = pk2(f2bf(f1.x), f2bf(f1.y)); vw.w = pk2(f2bf(f1.z), f2bf(f1.w));
      wf[nt][kt] = __builtin_bit_cast(bf16x8, vw);
    }
  // init ctx
  const int b2 = tid >> 6, o2 = (tid & 63) * 4;
  {
    float4 c4 = *(const float4*)(prev_ctx + b2 * CDIM + o2);
    ushort4 u; u.x = f2bf(c4.x); u.y = f2bf(c4.y); u.z = f2bf(c4.z); u.w = f2bf(c4.w);
    *(ushort4*)&ctx_lds[b2 * 288 + o2] = u;
  }
  float4 cw = *(const float4*)(cn_w + o2);
  float4 cb = *(const float4*)(cn_b + o2);
  bf16x8 af[8] = {};                       // rows 4..15 of A stay zero
  __syncthreads();

  for (int t = 0; t < SEQ; ++t) {
    float4 p4 = *(const float4*)(P + ((size_t)b2 * SEQ + t) * CDIM + o2);  // prefetch
    if (l15 < 4) {
#pragma unroll
      for (int kt = 0; kt < 8; ++kt)
        af[kt] = __builtin_bit_cast(bf16x8, *(const uint4*)(&ctx_lds[l15 * 288 + kt * 32 + lhi * 8]));
    }
    f32x4 acc[4] = {};
#pragma unroll
    for (int nt = 0; nt < 4; ++nt)
#pragma unroll
      for (int kt = 0; kt < 8; ++kt)
        acc[nt] = mfma16(af[kt], wf[nt][kt], acc[nt]);
    if (lane < 16) {                       // rows 0..3 (= batches) live in lanes 0..15
#pragma unroll
      for (int nt = 0; nt < 4; ++nt)
#pragma unroll
        for (int r = 0; r < 4; ++r)
          h_lds[r * 256 + wave * 64 + nt * 16 + lane] = acc[nt][r];
    }
    __syncthreads();
    // phase 2: gelu + LN, wave = one batch
    float4 h4 = *(const float4*)&h_lds[b2 * 256 + o2];
    float g0 = gelu_f(h4.x + p4.x), g1 = gelu_f(h4.y + p4.y);
    float g2 = gelu_f(h4.z + p4.z), g3 = gelu_f(h4.w + p4.w);
    float sm = g0 + g1 + g2 + g3;
    float sq = g0*g0 + g1*g1 + g2*g2 + g3*g3;
#pragma unroll
    for (int msk = 1; msk <= 32; msk <<= 1) { sm += __shfl_xor(sm, msk); sq += __shfl_xor(sq, msk); }
    float mean = sm * (1.f / CDIM);
    float var  = sq * (1.f / CDIM) - mean * mean;
    float inv  = rsqrtf(var + 1e-5f);
    float y0 = (g0 - mean) * inv * cw.x + cb.x;
    float y1 = (g1 - mean) * inv * cw.y + cb.y;
    float y2 = (g2 - mean) * inv * cw.z + cb.z;
    float y3 = (g3 - mean) * inv * cw.w + cb.w;
    float4 y; y.x = y0; y.y = y1; y.z = y2; y.w = y3;
    *(float4*)(x + ((size_t)b2 * SEQ + t) * CDIM + o2) = y;
    ushort4 u; u.x = f2bf(y0); u.y = f2bf(y1); u.z = f2bf(y2); u.w = f2bf(y3);
    *(ushort4*)&ctx_lds[b2 * 288 + o2] = u;
    __syncthreads();
  }
}

// ---------------------------------------------------------------- qkv rearrange + RoPE (ROT=8)
__global__ __launch_bounds__(256) void rope_k(const ushort* __restrict__ qkv,
                                              ushort* __restrict__ Qo,
                                              ushort* __restrict__ Ko,
                                              ushort* __restrict__ Vt) {
  int m = blockIdx.x;                      // b*S + s
  int b = m >> 10, s = m & 1023;
  int t = threadIdx.x;
  int h = t >> 5, d = t & 31;
  const ushort* row = qkv + (size_t)m * 768;
  float q = bf2f(row[h * 32 + d]);
  float k = bf2f(row[256 + h * 32 + d]);
  float v = bf2f(row[512 + h * 32 + d]);
  if (d < 8) {
    int prt = (d < 4) ? d + 4 : d - 4;
    float sgn = (d < 4) ? -1.f : 1.f;
    float qp = sgn * bf2f(row[h * 32 + prt]);
    float kp = sgn * bf2f(row[256 + h * 32 + prt]);
    int j = d & 3;
    float inv = powf(10000.f, -0.25f * (float)j);
    float ang = (float)s * inv;
    float c = cosf(ang), sn = sinf(ang);
    q = q * c + qp * sn;
    k = k * c + kp * sn;
  }
  size_t bh = (size_t)(b * NHEAD + h);
  Qo[(bh * SEQ + s) * HDIM + d] = f2bf(q);
  Ko[(bh * SEQ + s) * HDIM + d] = f2bf(k);
  Vt[bh * HDIM * SEQ + (size_t)d * SEQ + s] = f2bf(v);   // V transposed: [bh][d][s]
}

// ---------------------------------------------------------------- causal flash attention, D=32, MFMA
__global__ __launch_bounds__(256) void attn_k(const ushort* __restrict__ Q,
                                              const ushort* __restrict__ K,
                                              const ushort* __restrict__ VT,
                                              ushort* __restrict__ O) {
  __shared__ __attribute__((aligned(16))) ushort Plds[4 * 16 * 32];  // per-wave 16x32 P tile
  const int tid = threadIdx.x, lane = tid & 63, wave = tid >> 6;
  const int bh = blockIdx.y;
  const int qtile = blockIdx.x * 4 + wave;
  const int q0 = qtile * 16;
  const int l15 = lane & 15, lhi = lane >> 4;
  const float scale = 0.17677669529663689f;   // 1/sqrt(32)

  bf16x8 qa = __builtin_bit_cast(bf16x8,
      *(const uint4*)(Q + ((size_t)bh * SEQ + q0 + l15) * HDIM + lhi * 8));
  const ushort* Kb = K + (size_t)bh * SEQ * HDIM;
  const ushort* Vb = VT + (size_t)bh * HDIM * SEQ;
  ushort* Pw = &Plds[wave * 512];

  f32x4 o0 = {}, o1 = {};
  float mrow[4] = {-1e30f, -1e30f, -1e30f, -1e30f};
  float lrow[4] = {};

  for (int kt = 0; kt <= qtile; kt += 2) {
    const bool t2 = (kt + 1 <= qtile);
    f32x4 z = {};
    bf16x8 kf0 = __builtin_bit_cast(bf16x8, *(const uint4*)(Kb + (size_t)(kt * 16 + l15) * HDIM + lhi * 8));
    f32x4 s0 = mfma16(qa, kf0, z);
    f32x4 s1 = {};
    if (t2) {
      bf16x8 kf1 = __builtin_bit_cast(bf16x8, *(const uint4*)(Kb + (size_t)((kt + 1) * 16 + l15) * HDIM + lhi * 8));
      s1 = mfma16(qa, kf1, z);
    }
    float p0[4], p1[4], mx[4];
#pragma unroll
    for (int r = 0; r < 4; ++r) {
      int qr = q0 + lhi * 4 + r;
      int kc0 = kt * 16 + l15;
      p0[r] = (kc0 <= qr) ? s0[r] * scale : -1e30f;
      p1[r] = (t2 && kc0 + 16 <= qr) ? s1[r] * scale : -1e30f;
      mx[r] = fmaxf(p0[r], p1[r]);
    }
#pragma unroll
    for (int msk = 1; msk <= 8; msk <<= 1)
#pragma unroll
      for (int r = 0; r < 4; ++r) mx[r] = fmaxf(mx[r], __shfl_xor(mx[r], msk));
    float rs[4];
#pragma unroll
    for (int r = 0; r < 4; ++r) {
      float mn = fmaxf(mrow[r], mx[r]);
      float alpha = __expf(mrow[r] - mn);
      mrow[r] = mn;
      p0[r] = __expf(p0[r] - mn);
      p1[r] = __expf(p1[r] - mn);
      rs[r] = p0[r] + p1[r];
      lrow[r] = lrow[r] * alpha;
      o0[r] *= alpha; o1[r] *= alpha;
    }
#pragma unroll
    for (int msk = 1; msk <= 8; msk <<= 1)
#pragma unroll
      for (int r = 0; r < 4; ++r) rs[r] += __shfl_xor(rs[r], msk);
#pragma unroll
    for (int r = 0; r < 4; ++r) lrow[r] += rs[r];
    // P -> LDS (transpose for PV A-fragment)
#pragma unroll
    for (int r = 0; r < 4; ++r) {
      Pw[(lhi * 4 + r) * 32 + l15]      = f2bf(p0[r]);
      Pw[(lhi * 4 + r) * 32 + 16 + l15] = f2bf(p1[r]);
    }
    bf16x8 pa  = __builtin_bit_cast(bf16x8, *(const uint4*)(&Pw[l15 * 32 + lhi * 8]));
    bf16x8 v0f = __builtin_bit_cast(bf16x8, *(const uint4*)(Vb + (size_t)l15 * SEQ + kt * 16 + lhi * 8));
    bf16x8 v1f = __builtin_bit_cast(bf16x8, *(const uint4*)(Vb + (size_t)(16 + l15) * SEQ + kt * 16 + lhi * 8));
    o0 = mfma16(pa, v0f, o0);
    o1 = mfma16(pa, v1f, o1);
  }
  const int b = bh >> 3, h = bh & 7;
#pragma unroll
  for (int r = 0; r < 4; ++r) {
    float inv = 1.f / lrow[r];
    int qr = q0 + lhi * 4 + r;
    size_t base = ((size_t)(b * SEQ + qr)) * CDIM + h * HDIM;
    O[base + l15]      = f2bf(o0[r] * inv);
    O[base + 16 + l15] = f2bf(o1[r] * inv);
  }
}

// ---------------------------------------------------------------- launcher
static size_t ws_take(size_t& o, size_t bytes) {
  size_t r = o;
  o += (bytes + 255) & ~(size_t)255;
  return r;
}

extern "C" void kernel_launch(void* const* d_in, const int* in_sizes, int n_in,
                              void* d_out, int out_size, void* d_ws, size_t ws_size,
                              hipStream_t stream) {
  (void)in_sizes; (void)n_in; (void)out_size; (void)ws_size;
  const int*   input_ids = (const int*)  d_in[0];
  const float* prev_ctx  = (const float*)d_in[1];
  const float* embed_w   = (const float*)d_in[2];
  const float* en_w      = (const float*)d_in[3];
  const float* en_b      = (const float*)d_in[4];
  const float* ctx_w     = (const float*)d_in[5];
  const float* ctx_b     = (const float*)d_in[6];
  const float* cn_w      = (const float*)d_in[7];
  const float* cn_b      = (const float*)d_in[8];
  const float* ln1_w     = (const float*)d_in[9];
  const float* ln1_b     = (const float*)d_in[10];
  const float* ln2_w     = (const float*)d_in[11];
  const float* ln2_b     = (const float*)d_in[12];
  const float* qkv_w     = (const float*)d_in[13];
  const float* qkv_b     = (const float*)d_in[14];
  const float* ao_w      = (const float*)d_in[15];
  const float* ao_b      = (const float*)d_in[16];
  const float* fc1_w     = (const float*)d_in[17];
  const float* fc1_b     = (const float*)d_in[18];
  const float* fc2_w     = (const float*)d_in[19];
  const float* fc2_b     = (const float*)d_in[20];
  const float* fln_w     = (const float*)d_in[21];
  const float* fln_b     = (const float*)d_in[22];
  const float* out_w     = (const float*)d_in[23];
  float* logits = (float*)d_out;

  char* ws = (char*)d_ws;
  size_t o = 0;
  ushort* WB_OUT = (ushort*)(ws + ws_take(o, (size_t)NVOC * CDIM * 2));
  ushort* TOK    = (ushort*)(ws + ws_take(o, (size_t)NROWS * EDIM * 2));
  float*  PBUF   = (float*) (ws + ws_take(o, (size_t)NROWS * CDIM * 4));
  float*  XBUF   = (float*) (ws + ws_take(o, (size_t)NROWS * CDIM * 4));
  ushort* AIN    = (ushort*)(ws + ws_take(o, (size_t)NROWS * CDIM * 2));
  ushort* MIN    = (ushort*)(ws + ws_take(o, (size_t)NROWS * CDIM * 2));
  ushort* QKVB   = (ushort*)(ws + ws_take(o, (size_t)NROWS * 768 * 2));
  ushort* QB     = (ushort*)(ws + ws_take(o, (size_t)NROWS * CDIM * 2));
  ushort* KB     = (ushort*)(ws + ws_take(o, (size_t)NROWS * CDIM * 2));
  ushort* VTB    = (ushort*)(ws + ws_take(o, (size_t)NROWS * CDIM * 2));
  ushort* OB     = (ushort*)(ws + ws_take(o, (size_t)NROWS * CDIM * 2));
  ushort* TBUF   = (ushort*)(ws + ws_take(o, (size_t)NROWS * IDIM * 2));
  ushort* XLN    = (ushort*)(ws + ws_take(o, (size_t)NROWS * CDIM * 2));

  // out_w -> bf16 (re-read 32x in logits GEMM)
  cvt_k<<<dim3(2048), dim3(256), 0, stream>>>(out_w, WB_OUT, NVOC * CDIM / 4);
  // tok = LN(embed[ids])
  embed_ln_k<<<dim3(NROWS), dim3(64), 0, stream>>>(input_ids, embed_w, en_w, en_b, TOK);
  // P = tok @ W_e^T + ctx_b   (W_e = ctx_w[:, 256:768], fp32 strided)
  gemm_k<GF_BIAS | GF_WF32><<<dim3(32, 2), dim3(256), 0, stream>>>(
      TOK, EDIM, (const void*)(ctx_w + 256), 768, ctx_b, (void*)PBUF, CDIM, EDIM);
  // sequential context scan -> x
  scan_k<<<dim3(1), dim3(256), 0, stream>>>(ctx_w, prev_ctx, PBUF, cn_w, cn_b, XBUF);

  for (int l = 0; l < NLAY; ++l) {
    ln_k<true><<<dim3(NROWS), dim3(64), 0, stream>>>(
        XBUF, ln1_w + l * CDIM, ln1_b + l * CDIM, ln2_w + l * CDIM, ln2_b + l * CDIM, AIN, MIN);
    gemm_k<GF_BIAS | GF_BF16O | GF_WF32><<<dim3(32, 6), dim3(256), 0, stream>>>(
        AIN, CDIM, (const void*)(qkv_w + (size_t)l * 768 * CDIM), CDIM,
        qkv_b + l * 768, (void*)QKVB, 768, CDIM);
    rope_k<<<dim3(NROWS), dim3(256), 0, stream>>>(QKVB, QB, KB, VTB);
    attn_k<<<dim3(16, 32), dim3(256), 0, stream>>>(QB, KB, VTB, OB);
    gemm_k<GF_BIAS | GF_ACC | GF_WF32><<<dim3(32, 2), dim3(256), 0, stream>>>(
        OB, CDIM, (const void*)(ao_w + (size_t)l * CDIM * CDIM), CDIM,
        ao_b + l * CDIM, (void*)XBUF, CDIM, CDIM);
    gemm_k<GF_BIAS | GF_GELU | GF_BF16O | GF_WF32><<<dim3(32, 8), dim3(256), 0, stream>>>(
        MIN, CDIM, (const void*)(fc1_w + (size_t)l * IDIM * CDIM), CDIM,
        fc1_b + l * IDIM, (void*)TBUF, IDIM, CDIM);
    gemm_k<GF_BIAS | GF_ACC | GF_WF32><<<dim3(32, 2), dim3(256), 0, stream>>>(
        TBUF, IDIM, (const void*)(fc2_w + (size_t)l * CDIM * IDIM), IDIM,
        fc2_b + l * CDIM, (void*)XBUF, CDIM, IDIM);
  }

  ln_k<false><<<dim3(NROWS), dim3(64), 0, stream>>>(
      XBUF, fln_w, fln_b, nullptr, nullptr, XLN, nullptr);
  gemm_k<0><<<dim3(32, 393), dim3(256), 0, stream>>>(
      XLN, CDIM, (const void*)WB_OUT, CDIM, nullptr, (void*)logits, NVOC, CDIM);
}